// Round 3
// baseline (153.323 us; speedup 1.0000x reference)
//
#include <hip/hip_runtime.h>

#define GAMMA 0.99f
#define LAM   0.95f

constexpr int BLOCK = 256;
constexpr int CHUNK = 8;           // timesteps per thread; requires T == BLOCK*CHUNK
constexpr int NWAVES = BLOCK / 64;

typedef float v4f __attribute__((ext_vector_type(4)));   // native vec for nontemporal ops
typedef int   v4i __attribute__((ext_vector_type(4)));

// One block per row (B blocks). Thread i owns columns [i*CHUNK, i*CHUNK+CHUNK).
// Backward linear recurrence parallelized via affine composition:
//   g[t] = delta[t] + c[t]*g[t+1]  ==>  chunk maps incoming g to a + m*g.
__global__ __launch_bounds__(BLOCK) void gae_scan_kernel(
    const float* __restrict__ rewards,
    const float* __restrict__ values,
    const float* __restrict__ next_value,
    const int*   __restrict__ done,
    float* __restrict__ adv_out,
    float* __restrict__ ret_out,
    int T)
{
    const int row  = blockIdx.x;
    const int tid  = threadIdx.x;
    const int lane = tid & 63;
    const int wave = tid >> 6;

    const long rowbase = (long)row * T;
    const int  col0    = tid * CHUNK;

    // ---- fully vectorized loads of this thread's chunk (all aligned) ----
    const v4f* r4 = reinterpret_cast<const v4f*>(rewards + rowbase + col0);
    const v4f* v4 = reinterpret_cast<const v4f*>(values  + rowbase + col0);
    const v4i* d4 = reinterpret_cast<const v4i*>(done    + rowbase + col0);
    v4f ra = r4[0], rb = r4[1];
    v4f va = v4[0], vb = v4[1];
    v4i da = d4[0], db = d4[1];

    float r[CHUNK], v[CHUNK];
    r[0]=ra.x; r[1]=ra.y; r[2]=ra.z; r[3]=ra.w;
    r[4]=rb.x; r[5]=rb.y; r[6]=rb.z; r[7]=rb.w;
    v[0]=va.x; v[1]=va.y; v[2]=va.z; v[3]=va.w;
    v[4]=vb.x; v[5]=vb.y; v[6]=vb.z; v[7]=vb.w;

    // ---- +1-shifted boundary elements via neighbor-lane shuffle ----
    // need done[col0+8] and values[col0+8] (or clamped/bootstrap at row end)
    int   dnext = __shfl_down(da.x, 1);   // next thread's done[col0']
    float vnext = __shfl_down(v[0], 1);   // next thread's values[col0']
    if (lane == 63) {
        if (col0 + CHUNK < T) {           // next thread lives in the next wave
            dnext = done[rowbase + col0 + CHUNK];
            vnext = values[rowbase + col0 + CHUNK];
        } else {                          // tid == BLOCK-1: row end
            dnext = db.w;                 // dcol clamps to T-1 (own last elem)
            vnext = next_value[row];      // bootstrap value
        }
    }

    // done[col0+1 .. col0+8]
    int dsh[CHUNK];
    dsh[0]=da.y; dsh[1]=da.z; dsh[2]=da.w; dsh[3]=db.x;
    dsh[4]=db.y; dsh[5]=db.z; dsh[6]=db.w; dsh[7]=dnext;

    // ---- delta[t] and c[t] ----
    float delta[CHUNK], c[CHUNK];
#pragma unroll
    for (int j = 0; j < CHUNK; ++j) {
        const float nnt = 1.0f - (float)dsh[j];
        const float nv  = (j < CHUNK - 1) ? v[j + 1] : vnext;
        delta[j] = r[j] + GAMMA * nv * nnt - v[j];
        c[j]     = (GAMMA * LAM) * nnt;
    }

    // ---- per-thread affine composition over the chunk (backward) ----
    float a = 0.0f, m = 1.0f;
#pragma unroll
    for (int j = CHUNK - 1; j >= 0; --j) {
        a = delta[j] + c[j] * a;
        m = c[j] * m;
    }

    // ---- wave-level inclusive SUFFIX scan of affine fns ----
    float sa = a, sm = m;
#pragma unroll
    for (int d = 1; d < 64; d <<= 1) {
        float oa = __shfl_down(sa, d);
        float om = __shfl_down(sm, d);
        if (lane + d < 64) { sa = sa + sm * oa; sm = sm * om; }
    }
    // exclusive-within-wave (composition of all higher lanes in this wave)
    float ea = __shfl_down(sa, 1);
    float em = __shfl_down(sm, 1);
    if (lane == 63) { ea = 0.0f; em = 1.0f; }

    // ---- cross-wave composition via LDS ----
    __shared__ float lds_a[NWAVES];
    __shared__ float lds_m[NWAVES];
    if (lane == 0) { lds_a[wave] = sa; lds_m[wave] = sm; }
    __syncthreads();

    float g = 0.0f;                       // gae entering from waves above this one
    for (int j = NWAVES - 1; j > wave; --j)
        g = lds_a[j] + lds_m[j] * g;
    float gin = ea + em * g;              // gae entering this thread's chunk

    // ---- replay: exact sequential recurrence over the chunk ----
    float adv[CHUNK];
#pragma unroll
    for (int j = CHUNK - 1; j >= 0; --j) {
        gin = delta[j] + c[j] * gin;
        adv[j] = gin;
    }

    // ---- vectorized nontemporal stores: advantages, returns = adv + values ----
    v4f* a4 = reinterpret_cast<v4f*>(adv_out + rowbase + col0);
    v4f* t4 = reinterpret_cast<v4f*>(ret_out + rowbase + col0);
    v4f o0; o0.x=adv[0]; o0.y=adv[1]; o0.z=adv[2]; o0.w=adv[3];
    v4f o1; o1.x=adv[4]; o1.y=adv[5]; o1.z=adv[6]; o1.w=adv[7];
    v4f s0; s0.x=adv[0]+v[0]; s0.y=adv[1]+v[1]; s0.z=adv[2]+v[2]; s0.w=adv[3]+v[3];
    v4f s1; s1.x=adv[4]+v[4]; s1.y=adv[5]+v[5]; s1.z=adv[6]+v[6]; s1.w=adv[7]+v[7];
    __builtin_nontemporal_store(o0, a4);
    __builtin_nontemporal_store(o1, a4 + 1);
    __builtin_nontemporal_store(s0, t4);
    __builtin_nontemporal_store(s1, t4 + 1);
}

// Fallback for shapes where T != BLOCK*CHUNK: one thread per row, sequential.
__global__ void gae_naive_kernel(
    const float* __restrict__ rewards,
    const float* __restrict__ values,
    const float* __restrict__ next_value,
    const int*   __restrict__ done,
    float* __restrict__ adv_out,
    float* __restrict__ ret_out,
    int B, int T)
{
    int row = blockIdx.x * blockDim.x + threadIdx.x;
    if (row >= B) return;
    long base = (long)row * T;
    float g = 0.0f;
    for (int t = T - 1; t >= 0; --t) {
        int dcol = (t + 1 < T) ? (t + 1) : (T - 1);
        float nnt = 1.0f - (float)done[base + dcol];
        float nv  = (t + 1 < T) ? values[base + t + 1] : next_value[row];
        float dl  = rewards[base + t] + GAMMA * nv * nnt - values[base + t];
        g = dl + (GAMMA * LAM) * nnt * g;
        adv_out[base + t] = g;
        ret_out[base + t] = g + values[base + t];
    }
}

extern "C" void kernel_launch(void* const* d_in, const int* in_sizes, int n_in,
                              void* d_out, int out_size, void* d_ws, size_t ws_size,
                              hipStream_t stream) {
    const float* rewards    = (const float*)d_in[0];
    const float* values     = (const float*)d_in[1];
    const float* next_value = (const float*)d_in[2];
    const int*   done       = (const int*)d_in[3];

    const int B = in_sizes[2];               // next_value is [B]
    const int T = in_sizes[0] / B;           // rewards is [B, T]

    float* adv = (float*)d_out;
    float* ret = adv + (long)B * T;

    if (T == BLOCK * CHUNK) {
        gae_scan_kernel<<<B, BLOCK, 0, stream>>>(
            rewards, values, next_value, done, adv, ret, T);
    } else {
        gae_naive_kernel<<<(B + 255) / 256, 256, 0, stream>>>(
            rewards, values, next_value, done, adv, ret, B, T);
    }
}